// Round 1
// baseline (2360.662 us; speedup 1.0000x reference)
//
#include <hip/hip_runtime.h>
#include <math.h>

#define NB   1024
#define NH   8
#define NDK  64
#define NDM  512
#define NP   49
#define NPP  52
#define KEEP 11

#define BM 128
#define BN 128
#define BK 16

// C[M][N] = A[M][K] @ B[N][K]^T + bias[N]   (both A and B are K-major)
__global__ __launch_bounds__(256) void sgemm_nt(
    const float* __restrict__ A,
    const float* __restrict__ B,
    const float* __restrict__ bias,
    float* __restrict__ C,
    int M, int N, int K)
{
    __shared__ float As[BK][BM + 4];
    __shared__ float Bs[BK][BN + 4];
    const int t  = threadIdx.x;
    const int tx = t & 15, ty = t >> 4;
    const int bm = blockIdx.y * BM, bn = blockIdx.x * BN;
    const float* Ab = A + (size_t)bm * K;
    const float* Bb = B + (size_t)bn * K;

    float acc[8][8];
#pragma unroll
    for (int i = 0; i < 8; ++i)
#pragma unroll
        for (int j = 0; j < 8; ++j) acc[i][j] = 0.f;

    for (int kt = 0; kt < K; kt += BK) {
#pragma unroll
        for (int u = 0; u < 2; ++u) {
            const int f   = t + u * 256;
            const int row = f >> 2;
            const int c0  = (f & 3) << 2;
            const float4 av = *(const float4*)(Ab + (size_t)row * K + kt + c0);
            const float4 bv = *(const float4*)(Bb + (size_t)row * K + kt + c0);
            As[c0 + 0][row] = av.x; As[c0 + 1][row] = av.y;
            As[c0 + 2][row] = av.z; As[c0 + 3][row] = av.w;
            Bs[c0 + 0][row] = bv.x; Bs[c0 + 1][row] = bv.y;
            Bs[c0 + 2][row] = bv.z; Bs[c0 + 3][row] = bv.w;
        }
        __syncthreads();
#pragma unroll
        for (int kk = 0; kk < BK; ++kk) {
            float a[8], b[8];
#pragma unroll
            for (int i = 0; i < 8; ++i) a[i] = As[kk][ty * 8 + i];
#pragma unroll
            for (int j = 0; j < 8; ++j) b[j] = Bs[kk][tx * 8 + j];
#pragma unroll
            for (int i = 0; i < 8; ++i)
#pragma unroll
                for (int j = 0; j < 8; ++j) acc[i][j] += a[i] * b[j];
        }
        __syncthreads();
    }

#pragma unroll
    for (int i = 0; i < 8; ++i) {
        const int r = bm + ty * 8 + i;
        float* Crow = C + (size_t)r * N + bn + tx * 8;
#pragma unroll
        for (int j4 = 0; j4 < 2; ++j4) {
            const int cb = bn + tx * 8 + j4 * 4;
            float4 o;
            o.x = acc[i][j4 * 4 + 0] + bias[cb + 0];
            o.y = acc[i][j4 * 4 + 1] + bias[cb + 1];
            o.z = acc[i][j4 * 4 + 2] + bias[cb + 2];
            o.w = acc[i][j4 * 4 + 3] + bias[cb + 3];
            *(float4*)(Crow + j4 * 4) = o;
        }
    }
}

// One block per (b,h). q/k/v buffers are [b][49][h*64+d] (plain GEMM layout).
// Writes mid[b][49][h*64+d]; mid may alias qbuf (each block writes only the
// h-slice that it alone reads, after staging it to LDS).
__global__ __launch_bounds__(256) void attn_mid(
    const float* __restrict__ qb,
    const float* __restrict__ kb,
    const float* __restrict__ vb,
    const float* __restrict__ Wg,
    const float* __restrict__ Vg,
    float* __restrict__ mid)
{
    const int bh = blockIdx.x;
    const int b = bh >> 3, h = bh & 7;

    __shared__ float qs[NPP][NDK];
    __shared__ float ks[NPP][NDK];
    __shared__ float vs[NPP][NDK];
    __shared__ float ss[NPP][NPP];
    __shared__ float rs[NPP];
    __shared__ float vRl[16];

    const int t = threadIdx.x;
    if (t < 13) {  // R in [0,12]; gate table (1+e^V)/(1+e^(V-W*R))
        const float Wh = Wg[h], Vh = Vg[h];
        vRl[t] = (1.f + expf(Vh)) / (1.f + expf(Vh - Wh * (float)t));
    }

    const size_t base = ((size_t)b * NP) * NDM + (size_t)h * NDK;
    for (int i = t; i < NPP * (NDK / 4); i += 256) {
        const int pos = i >> 4;
        const int c0  = (i & 15) << 2;
        float4 zq = make_float4(0.f, 0.f, 0.f, 0.f);
        float4 zk = zq, zv = zq;
        if (pos < NP) {
            const size_t off = base + (size_t)pos * NDM + c0;
            zq = *(const float4*)(qb + off);
            zk = *(const float4*)(kb + off);
            zv = *(const float4*)(vb + off);
        }
        *(float4*)&qs[pos][c0] = zq;
        *(float4*)&ks[pos][c0] = zk;
        *(float4*)&vs[pos][c0] = zv;
    }
    __syncthreads();

    // phase 1: ss = 0.125 * q @ k^T  (exact scaling: 0.125 is a power of 2)
    if (t < 169) {
        const int r0 = (t / 13) * 4;
        const int c0 = (t % 13) * 4;
        float acc[4][4];
#pragma unroll
        for (int i = 0; i < 4; ++i)
#pragma unroll
            for (int j = 0; j < 4; ++j) acc[i][j] = 0.f;
        for (int kk = 0; kk < NDK; kk += 4) {
            float4 a[4], bb[4];
#pragma unroll
            for (int i = 0; i < 4; ++i) a[i]  = *(const float4*)&qs[r0 + i][kk];
#pragma unroll
            for (int j = 0; j < 4; ++j) bb[j] = *(const float4*)&ks[c0 + j][kk];
#pragma unroll
            for (int i = 0; i < 4; ++i)
#pragma unroll
                for (int j = 0; j < 4; ++j)
                    acc[i][j] += a[i].x * bb[j].x + a[i].y * bb[j].y
                               + a[i].z * bb[j].z + a[i].w * bb[j].w;
        }
#pragma unroll
        for (int i = 0; i < 4; ++i)
#pragma unroll
            for (int j = 0; j < 4; ++j)
                ss[r0 + i][c0 + j] = acc[i][j] * 0.125f;
    }
    __syncthreads();

    // phase 2: per-row top-11 threshold (39th smallest), softmax #1, map,
    // round -> cell, gated logits, softmax #2 numerators (one thread per row)
    if (t < NP) {
        const int r = t;
        float top[KEEP];
#pragma unroll
        for (int i = 0; i < KEEP; ++i) top[i] = -INFINITY;
        for (int c = 0; c < NP; ++c) {
            float x = ss[r][c];
#pragma unroll
            for (int i = 0; i < KEEP; ++i) {  // descending insertion bubble
                const float hi = fmaxf(top[i], x);
                const float lo = fminf(top[i], x);
                top[i] = hi; x = lo;
            }
        }
        const float kth = top[KEEP - 1];   // 11th largest == 39th smallest
        const float m1  = top[0];
        float sum = 0.f, mi = 0.f, mj = 0.f;
        for (int c = 0; c < NP; ++c) {
            const float x = ss[r][c];
            if (x >= kth) {                 // keep ties, like att < kth -> -inf
                const float e = expf(x - m1);
                sum += e;
                mi  += e * (float)(c / 7);
                mj  += e * (float)(c % 7);
            }
        }
        mi /= sum; mj /= sum;
        const int pi = (int)rintf(mi);      // rintf == round-half-even == jnp.round
        const int pj = (int)rintf(mj);

        // logits2 = relu(scores)*vR*scale == relu(ss)*vR  (bit-exact equiv)
        float m2 = 0.f;
        for (int c = 0; c < NP; ++c) {
            const int ci = c / 7, cj = c % 7;
            const int R  = abs(pi - ci) + abs(pj - cj);
            const float l = fmaxf(ss[r][c], 0.f) * vRl[R];
            ss[r][c] = l;
            m2 = fmaxf(m2, l);
        }
        float s2 = 0.f;
        for (int c = 0; c < NP; ++c) {
            const float e2 = expf(ss[r][c] - m2);
            ss[r][c] = e2;
            s2 += e2;
        }
        rs[r] = 1.f / s2;
    }
    __syncthreads();

    // phase 3: mid_slice = diag(rs) * ss @ vs
    if (t < 208) {
        const int tr = t >> 4;           // rows 4tr..4tr+3
        const int d0 = (t & 15) << 2;    // output dim 0..60
        float acc[4][4];
#pragma unroll
        for (int i = 0; i < 4; ++i)
#pragma unroll
            for (int j = 0; j < 4; ++j) acc[i][j] = 0.f;
        for (int c = 0; c < NP; ++c) {
            const float4 vv = *(const float4*)&vs[c][d0];
            float p[4];
#pragma unroll
            for (int i = 0; i < 4; ++i) p[i] = ss[4 * tr + i][c];
#pragma unroll
            for (int i = 0; i < 4; ++i) {
                acc[i][0] += p[i] * vv.x;
                acc[i][1] += p[i] * vv.y;
                acc[i][2] += p[i] * vv.z;
                acc[i][3] += p[i] * vv.w;
            }
        }
#pragma unroll
        for (int i = 0; i < 4; ++i) {
            const int r = 4 * tr + i;
            if (r < NP) {
                const float sc = rs[r];
                float4 o;
                o.x = acc[i][0] * sc; o.y = acc[i][1] * sc;
                o.z = acc[i][2] * sc; o.w = acc[i][3] * sc;
                *(float4*)(mid + base + (size_t)r * NDM + d0) = o;
            }
        }
    }
}

extern "C" void kernel_launch(void* const* d_in, const int* in_sizes, int n_in,
                              void* d_out, int out_size, void* d_ws, size_t ws_size,
                              hipStream_t stream)
{
    (void)in_sizes; (void)n_in; (void)out_size; (void)ws_size;
    const float* queries = (const float*)d_in[0];
    const float* keys    = (const float*)d_in[1];
    const float* values  = (const float*)d_in[2];
    const float* Wq = (const float*)d_in[3];
    const float* bq = (const float*)d_in[4];
    const float* Wk = (const float*)d_in[5];
    const float* bk = (const float*)d_in[6];
    const float* Wv = (const float*)d_in[7];
    const float* bv = (const float*)d_in[8];
    const float* Wo = (const float*)d_in[9];
    const float* bo = (const float*)d_in[10];
    const float* Wg = (const float*)d_in[11];
    const float* Vg = (const float*)d_in[12];
    float* out = (float*)d_out;

    float* ws = (float*)d_ws;
    const size_t SZ = (size_t)NB * NP * NDM;   // 25,690,112 elements
    float* qbuf = ws;
    float* kbuf = ws + SZ;
    float* vbuf = ws + 2 * SZ;
    float* mid  = qbuf;                        // safe alias (see attn_mid)

    const int M = NB * NP;                     // 50176
    dim3 blk(256);
    dim3 ggrid(NDM / BN, M / BM);              // (4, 392)

    hipLaunchKernelGGL(sgemm_nt, ggrid, blk, 0, stream, queries, Wq, bq, qbuf, M, NDM, NDM);
    hipLaunchKernelGGL(sgemm_nt, ggrid, blk, 0, stream, keys,    Wk, bk, kbuf, M, NDM, NDM);
    hipLaunchKernelGGL(sgemm_nt, ggrid, blk, 0, stream, values,  Wv, bv, vbuf, M, NDM, NDM);
    hipLaunchKernelGGL(attn_mid, dim3(NB * NH), blk, 0, stream, qbuf, kbuf, vbuf, Wg, Vg, mid);
    hipLaunchKernelGGL(sgemm_nt, ggrid, blk, 0, stream, mid, Wo, bo, out, M, NDM, NDM);
}